// Round 11
// baseline (1426.941 us; speedup 1.0000x reference)
//
#include <hip/hip_runtime.h>

#define NH    20000
#define NF    200000
#define DHOST 64
#define DFLOW 128
#define DHID  256
#define NE    2000000
#define NLAYER 2

typedef __attribute__((ext_vector_type(8))) short s16x8;
typedef __attribute__((ext_vector_type(4))) float f32x4;

__device__ __forceinline__ unsigned short f2bf(float x) {
    unsigned u = __builtin_bit_cast(unsigned, x);
    unsigned r = (u + 0x7fffu + ((u >> 16) & 1u)) >> 16;
    return (unsigned short)r;
}
__device__ __forceinline__ float bf2f(unsigned short h) {
    unsigned u = ((unsigned)h) << 16;
    return __builtin_bit_cast(float, u);
}

typedef const __attribute__((address_space(1))) unsigned int guint;
typedef __attribute__((address_space(3))) unsigned int luint;
__device__ __forceinline__ void gld16(const void* g, void* l) {
    __builtin_amdgcn_global_load_lds((guint*)g, (luint*)l, 16, 0, 0);
}

// ---------------- small utils ----------------
__global__ void zero_k(int* __restrict__ p, int n) {
    int i = blockIdx.x * 256 + threadIdx.x;
    if (i < n) p[i] = 0;
}

__global__ __launch_bounds__(256) void cvt_bf16_k(const float* __restrict__ in, unsigned short* __restrict__ out, int n4) {
    int i = blockIdx.x * 256 + threadIdx.x;
    if (i < n4) {
        float4 v = *reinterpret_cast<const float4*>(in + (size_t)i * 4);
        ushort4 o;
        o.x = f2bf(v.x); o.y = f2bf(v.y); o.z = f2bf(v.z); o.w = f2bf(v.w);
        *reinterpret_cast<ushort4*>(out + (size_t)i * 4) = o;
    }
}

// W [K][256] f32 -> Wt [256][K] bf16 ; grid (8, K/32, nmat), block 256
__global__ __launch_bounds__(256) void tpose_k(const float* __restrict__ W, unsigned short* __restrict__ Wt, int K) {
    __shared__ float T[32][33];
    int bx = blockIdx.x, by = blockIdx.y;
    const float* Wz = W + (size_t)blockIdx.z * K * 256;
    unsigned short* Wtz = Wt + (size_t)blockIdx.z * K * 256;
    int tx = threadIdx.x & 31, ty = threadIdx.x >> 5;
#pragma unroll
    for (int i = 0; i < 4; ++i) {
        int k = by * 32 + ty + i * 8;
        T[ty + i * 8][tx] = Wz[(size_t)k * 256 + bx * 32 + tx];
    }
    __syncthreads();
#pragma unroll
    for (int i = 0; i < 4; ++i) {
        int n = bx * 32 + ty + i * 8;
        Wtz[(size_t)n * K + by * 32 + tx] = f2bf(T[tx][ty + i * 8]);
    }
}

// exclusive scan, single block (n <= 1024), 256 threads x 4
__global__ void scan1_k(const int* __restrict__ in, int n, int* __restrict__ out, int* __restrict__ bsum) {
    __shared__ int wsum[4];
    int t = threadIdx.x;
    int lane = t & 63, wave = t >> 6;
    int idx = blockIdx.x * 1024 + t * 4;
    int v[4]; int s = 0;
#pragma unroll
    for (int i = 0; i < 4; ++i) { v[i] = (idx + i < n) ? in[idx + i] : 0; s += v[i]; }
    int inc = s;
#pragma unroll
    for (int off = 1; off < 64; off <<= 1) { int u = __shfl_up(inc, off); if (lane >= off) inc += u; }
    if (lane == 63) wsum[wave] = inc;
    __syncthreads();
    int woff = 0;
    for (int w = 0; w < wave; ++w) woff += wsum[w];
    int ex = woff + inc - s;
#pragma unroll
    for (int i = 0; i < 4; ++i) { if (idx + i < n) out[idx + i] = ex; ex += v[i]; }
    if (t == 255) bsum[blockIdx.x] = woff + inc;
}

// ---------------- bucketed CSR build (both graphs per launch) ----------------
__global__ __launch_bounds__(256) void histAB(const int* __restrict__ dstA, const int* __restrict__ dstB,
                                              int E, int* __restrict__ gbhA, int* __restrict__ gbhB) {
    __shared__ int lh[391];
    const int g = blockIdx.y;
    const int* dst = g ? dstB : dstA;
    int* gbh = g ? gbhB : gbhA;
    const int SH = g ? 6 : 9;
    const int NBKT = g ? 313 : 391;
    for (int b = threadIdx.x; b < NBKT; b += 256) lh[b] = 0;
    __syncthreads();
#pragma unroll
    for (int k = 0; k < 8; ++k) {
        int i = blockIdx.x * 2048 + k * 256 + threadIdx.x;
        if (i < E) atomicAdd(&lh[dst[i] >> SH], 1);
    }
    __syncthreads();
    for (int b = threadIdx.x; b < NBKT; b += 256) if (lh[b]) atomicAdd(&gbh[b], lh[b]);
}

__global__ void initcur_k(int* __restrict__ bko, int* __restrict__ gcur, int nbkt, int E) {
    int i = blockIdx.x * 256 + threadIdx.x;
    if (i < nbkt) gcur[i] = bko[i];
    if (i == nbkt) bko[nbkt] = E;
}

__global__ __launch_bounds__(256) void binpassAB(const int* __restrict__ srcA, const int* __restrict__ dstA,
                                                 const int* __restrict__ srcB, const int* __restrict__ dstB,
                                                 int E, int* __restrict__ gcurA, int* __restrict__ gcurB,
                                                 int* __restrict__ pairsA, int* __restrict__ pairsB) {
    __shared__ int lh[391], resv[391], lc[391];
    const int g = blockIdx.y;
    const int* src = g ? srcB : srcA;
    const int* dst = g ? dstB : dstA;
    int* gcur = g ? gcurB : gcurA;
    int* pairs = g ? pairsB : pairsA;
    const int SH = g ? 6 : 9;
    const int NBKT = g ? 313 : 391;
    const int MSK = (1 << SH) - 1;
    const int tid = threadIdx.x;
    const int e0 = blockIdx.x * 8192;
    for (int b = tid; b < NBKT; b += 256) { lh[b] = 0; lc[b] = 0; }
    __syncthreads();
#pragma unroll 4
    for (int k = 0; k < 32; ++k) {
        int i = e0 + k * 256 + tid;
        if (i < E) atomicAdd(&lh[dst[i] >> SH], 1);
    }
    __syncthreads();
    for (int b = tid; b < NBKT; b += 256) if (lh[b]) resv[b] = atomicAdd(&gcur[b], lh[b]);
    __syncthreads();
#pragma unroll 4
    for (int k = 0; k < 32; ++k) {
        int i = e0 + k * 256 + tid;
        if (i < E) {
            int d = dst[i];
            int b = d >> SH;
            int p = resv[b] + atomicAdd(&lc[b], 1);
            pairs[p] = src[i] | ((d & MSK) << 18);
        }
    }
}

template<int SH, int NPB>
__global__ __launch_bounds__(256) void csrfin(const int* __restrict__ pairs, const int* __restrict__ bko,
                                              int N, int E, int* __restrict__ rowptr, int* __restrict__ col) {
    __shared__ int cnt[NPB], pos[NPB];
    __shared__ int wsum[4];
    const int tid = threadIdx.x;
    const int b = blockIdx.x;
    const int nb = b << SH;
    const int beg = bko[b], end = bko[b + 1];
    for (int i = tid; i < NPB; i += 256) cnt[i] = 0;
    __syncthreads();
    for (int i = beg + tid; i < end; i += 256) atomicAdd(&cnt[pairs[i] >> 18], 1);
    __syncthreads();
    int lane = tid & 63, wave = tid >> 6;
    if (NPB == 512) {
        int a = cnt[2 * tid], b2 = cnt[2 * tid + 1];
        int s = a + b2, incl = s;
#pragma unroll
        for (int off = 1; off < 64; off <<= 1) { int u = __shfl_up(incl, off); if (lane >= off) incl += u; }
        if (lane == 63) wsum[wave] = incl;
        __syncthreads();
        int woff = 0;
        for (int w = 0; w < wave; ++w) woff += wsum[w];
        int ex = woff + incl - s;
        pos[2 * tid] = ex; pos[2 * tid + 1] = ex + a;
    } else {
        if (tid < NPB) {
            int a = cnt[tid], incl = a;
#pragma unroll
            for (int off = 1; off < 64; off <<= 1) { int u = __shfl_up(incl, off); if (lane >= off) incl += u; }
            pos[tid] = incl - a;
        }
    }
    __syncthreads();
    for (int i = tid; i < NPB; i += 256) {
        int node = nb + i;
        if (node < N) rowptr[node] = beg + pos[i];
    }
    if (b == gridDim.x - 1 && tid == 0) rowptr[N] = E;
    __syncthreads();
    for (int i = beg + tid; i < end; i += 256) {
        int pk = pairs[i];
        int p = atomicAdd(&pos[pk >> 18], 1);
        col[beg + p] = pk & 0x3FFFF;
    }
}

// ---------------- mean aggregation, 8-deep MLP (high-degree fh graph) ----------------
__global__ __launch_bounds__(256) void agg8_bf16(const unsigned short* __restrict__ srcFeat,
                                                 const int* __restrict__ rowptr,
                                                 const int* __restrict__ col,
                                                 unsigned short* __restrict__ outp, int n) {
    int w = (blockIdx.x << 2) + (threadIdx.x >> 6);
    if (w >= n) return;
    int lane = threadIdx.x & 63;
    int half = lane >> 5, l5 = lane & 31;
    int beg = rowptr[w], end = rowptr[w + 1];
    int T = end - beg;
    const unsigned short* base = srcFeat + l5 * 8;
    float a0[8], a1[8], a2[8], a3[8], a4[8], a5[8], a6[8], a7[8];
#pragma unroll
    for (int j = 0; j < 8; ++j) {
        a0[j] = 0.f; a1[j] = 0.f; a2[j] = 0.f; a3[j] = 0.f;
        a4[j] = 0.f; a5[j] = 0.f; a6[j] = 0.f; a7[j] = 0.f;
    }
    int i = beg;
    int nb16 = T >> 4;
    {
        const int* cp = col + beg + half * 8;
        for (int k = 0; k < nb16; ++k) {
            int c0 = cp[k * 16 + 0], c1 = cp[k * 16 + 1], c2 = cp[k * 16 + 2], c3 = cp[k * 16 + 3];
            int c4 = cp[k * 16 + 4], c5 = cp[k * 16 + 5], c6 = cp[k * 16 + 6], c7 = cp[k * 16 + 7];
            s16x8 v0 = *reinterpret_cast<const s16x8*>(base + (size_t)c0 * DHID);
            s16x8 v1 = *reinterpret_cast<const s16x8*>(base + (size_t)c1 * DHID);
            s16x8 v2 = *reinterpret_cast<const s16x8*>(base + (size_t)c2 * DHID);
            s16x8 v3 = *reinterpret_cast<const s16x8*>(base + (size_t)c3 * DHID);
            s16x8 v4 = *reinterpret_cast<const s16x8*>(base + (size_t)c4 * DHID);
            s16x8 v5 = *reinterpret_cast<const s16x8*>(base + (size_t)c5 * DHID);
            s16x8 v6 = *reinterpret_cast<const s16x8*>(base + (size_t)c6 * DHID);
            s16x8 v7 = *reinterpret_cast<const s16x8*>(base + (size_t)c7 * DHID);
#pragma unroll
            for (int j = 0; j < 8; ++j) {
                a0[j] += bf2f((unsigned short)v0[j]);
                a1[j] += bf2f((unsigned short)v1[j]);
                a2[j] += bf2f((unsigned short)v2[j]);
                a3[j] += bf2f((unsigned short)v3[j]);
                a4[j] += bf2f((unsigned short)v4[j]);
                a5[j] += bf2f((unsigned short)v5[j]);
                a6[j] += bf2f((unsigned short)v6[j]);
                a7[j] += bf2f((unsigned short)v7[j]);
            }
        }
    }
    i += nb16 * 16;
    if (end - i >= 8) {
        const int* cp = col + i + half * 4;
        int c0 = cp[0], c1 = cp[1], c2 = cp[2], c3 = cp[3];
        s16x8 v0 = *reinterpret_cast<const s16x8*>(base + (size_t)c0 * DHID);
        s16x8 v1 = *reinterpret_cast<const s16x8*>(base + (size_t)c1 * DHID);
        s16x8 v2 = *reinterpret_cast<const s16x8*>(base + (size_t)c2 * DHID);
        s16x8 v3 = *reinterpret_cast<const s16x8*>(base + (size_t)c3 * DHID);
#pragma unroll
        for (int j = 0; j < 8; ++j) {
            a0[j] += bf2f((unsigned short)v0[j]);
            a1[j] += bf2f((unsigned short)v1[j]);
            a2[j] += bf2f((unsigned short)v2[j]);
            a3[j] += bf2f((unsigned short)v3[j]);
        }
        i += 8;
    }
    for (int e = i + half; e < end; e += 2) {
        int c = col[e];
        s16x8 v = *reinterpret_cast<const s16x8*>(base + (size_t)c * DHID);
#pragma unroll
        for (int j = 0; j < 8; ++j) a0[j] += bf2f((unsigned short)v[j]);
    }
    int deg = T > 0 ? T : 1;
    float inv = 1.0f / (float)deg;
    s16x8 o;
#pragma unroll
    for (int j = 0; j < 8; ++j) {
        float s = ((a0[j] + a1[j]) + (a2[j] + a3[j])) + ((a4[j] + a5[j]) + (a6[j] + a7[j]));
        s += __shfl_xor(s, 32);
        o[j] = (short)f2bf(s * inv);
    }
    if (half == 0)
        *reinterpret_cast<s16x8*>(outp + (size_t)w * DHID + l5 * 8) = o;
}

// ---------------- MFMA bf16 GEMM, N fixed at 256 ----------------
__device__ __forceinline__ unsigned swz(unsigned r, unsigned cb) {
    return r * 128u + (cb ^ ((r & 7u) << 4));
}

template<int KP>
__device__ __forceinline__ void mfma_pass(const unsigned short* A, const unsigned short* Wt,
                                          int m0, int M, int tid, int lane, int wr, int wc,
                                          f32x4 (&acc)[4][4], char* AsB, char* BsB) {
    const int wave = tid >> 6;
    for (int k0 = 0; k0 < KP; k0 += 64) {
        __syncthreads();
#pragma unroll
        for (int i = 0; i < 2; ++i) {
            int u = wave * 2 + i;
            int r = u * 8 + (lane >> 3);
            int gr = m0 + r; if (gr >= M) gr = M - 1;
            int gs = (lane & 7) ^ (r & 7);
            gld16(A + (size_t)gr * KP + k0 + gs * 8, AsB + u * 1024);
        }
#pragma unroll
        for (int i = 0; i < 4; ++i) {
            int u = wave * 4 + i;
            int nn = u * 8 + (lane >> 3);
            int gs = (lane & 7) ^ (nn & 7);
            gld16(Wt + (size_t)nn * KP + k0 + gs * 8, BsB + u * 1024);
        }
        __syncthreads();
#pragma unroll
        for (int kk = 0; kk < 2; ++kk) {
            s16x8 ar[4], br[4];
            unsigned colb = (unsigned)(kk * 64 + (lane >> 4) * 16);
#pragma unroll
            for (int mf = 0; mf < 4; ++mf)
                ar[mf] = *reinterpret_cast<const s16x8*>(AsB + swz((unsigned)(wr * 64 + mf * 16 + (lane & 15)), colb));
#pragma unroll
            for (int nf = 0; nf < 4; ++nf)
                br[nf] = *reinterpret_cast<const s16x8*>(BsB + swz((unsigned)(wc * 64 + nf * 16 + (lane & 15)), colb));
#pragma unroll
            for (int mf = 0; mf < 4; ++mf)
#pragma unroll
                for (int nf = 0; nf < 4; ++nf)
                    acc[mf][nf] = __builtin_amdgcn_mfma_f32_16x16x32_bf16(ar[mf], br[nf], acc[mf][nf], 0, 0, 0);
        }
    }
}

// BL=0: row-major out [M][256]; BL=1: column-blocked out [4][M][64] (block q = col>>6)
template<int K1, int ACT, int FUSE, int BL>
__global__ __launch_bounds__(512) void mgemm(const unsigned short* A1, const unsigned short* W1t,
                                             const float* __restrict__ bias,
                                             const unsigned short* A2, const unsigned short* W2t,
                                             unsigned short* outp, int M) {
    __shared__ char AsB[128 * 64 * 2];
    __shared__ char BsB[256 * 64 * 2];
    const int tid = threadIdx.x;
    const int lane = tid & 63, wave = tid >> 6;
    const int wr = wave >> 2, wc = wave & 3;
    const int m0 = blockIdx.x * 128;
    f32x4 acc[4][4];
#pragma unroll
    for (int a = 0; a < 4; ++a)
#pragma unroll
        for (int b = 0; b < 4; ++b) acc[a][b] = (f32x4)0.0f;

    mfma_pass<K1>(A1, W1t, m0, M, tid, lane, wr, wc, acc, AsB, BsB);
    if (FUSE) mfma_pass<DHID>(A2, W2t, m0, M, tid, lane, wr, wc, acc, AsB, BsB);

    const int col0 = wc * 64 + (lane & 15);
    float bc[4];
#pragma unroll
    for (int nf = 0; nf < 4; ++nf) bc[nf] = bias[col0 + nf * 16];
#pragma unroll
    for (int mf = 0; mf < 4; ++mf) {
        int row = m0 + wr * 64 + mf * 16 + (lane >> 4) * 4;
#pragma unroll
        for (int j = 0; j < 4; ++j) {
            if (row + j < M) {
#pragma unroll
                for (int nf = 0; nf < 4; ++nf) {
                    float v = acc[mf][nf][j] + bc[nf];
                    if (ACT == 1) v = fmaxf(v, 0.0f);
                    else if (ACT == 2) v = v > 0.0f ? v : 0.01f * v;
                    if (BL)
                        outp[(size_t)wc * M * 64 + (size_t)(row + j) * 64 + (lane & 15) + nf * 16] = f2bf(v);
                    else
                        outp[(size_t)(row + j) * DHID + col0 + nf * 16] = f2bf(v);
                }
            }
        }
    }
}

// ---------------- fused flow update: F = leaky(F@Wr + b + mean_agg(Hp)) ----------------
// GEMM -> bf16 tile in LDS -> 4 column-block gather passes (table 2.5 MB, L2-resident).
__global__ __launch_bounds__(512) void mgemm_fa(const unsigned short* Fin, const unsigned short* Wrt,
                                                const float* __restrict__ bias,
                                                const unsigned short* __restrict__ Hpb,  // [4][NH][64]
                                                const int* __restrict__ rowptr,
                                                const int* __restrict__ colv,
                                                unsigned short* Fout, int M) {
    __shared__ union {
        struct { char A[128 * 128]; char B[256 * 128]; } st;   // 48 KB staging
        unsigned short tile[128][256];                         // 64 KB root-term tile
    } sm;
    const int tid = threadIdx.x;
    const int lane = tid & 63, wave = tid >> 6;
    const int wr = wave >> 2, wc = wave & 3;
    const int m0 = blockIdx.x * 128;
    f32x4 acc[4][4];
#pragma unroll
    for (int a = 0; a < 4; ++a)
#pragma unroll
        for (int b = 0; b < 4; ++b) acc[a][b] = (f32x4)0.0f;

    mfma_pass<DHID>(Fin, Wrt, m0, M, tid, lane, wr, wc, acc, sm.st.A, sm.st.B);
    __syncthreads();   // staging reads done before tile overwrites the union

    // epilogue -> LDS tile (bias added, no activation yet)
    const int col0 = wc * 64 + (lane & 15);
    float bc[4];
#pragma unroll
    for (int nf = 0; nf < 4; ++nf) bc[nf] = bias[col0 + nf * 16];
#pragma unroll
    for (int mf = 0; mf < 4; ++mf) {
        int rl = wr * 64 + mf * 16 + (lane >> 4) * 4;
#pragma unroll
        for (int j = 0; j < 4; ++j)
#pragma unroll
            for (int nf = 0; nf < 4; ++nf)
                sm.tile[rl + j][col0 + nf * 16] = f2bf(acc[mf][nf][j] + bc[nf]);
    }
    __syncthreads();

    // gather: 4 passes over column blocks; per node: 8 edge-groups x 8 lanes(16B)
    const int e8 = lane >> 3, c8 = lane & 7;
    for (int q = 0; q < 4; ++q) {
        const unsigned short* tb = Hpb + (size_t)q * NH * 64 + c8 * 8;
        for (int t = 0; t < 16; ++t) {
            int local = wave * 16 + t;
            int node = m0 + local;
            if (node >= M) break;                 // wave-uniform
            int beg = rowptr[node];
            int deg = rowptr[node + 1] - beg;
            float a[8];
#pragma unroll
            for (int j = 0; j < 8; ++j) a[j] = 0.0f;
            int nb = (deg + 7) >> 3;
            for (int k = 0; k < nb; k += 2) {
                int i0 = k * 8 + e8, i1 = i0 + 8;
                int ee0 = beg + i0; if (ee0 > NE - 1) ee0 = NE - 1;
                int ee1 = beg + i1; if (ee1 > NE - 1) ee1 = NE - 1;
                int r0 = colv[ee0], r1 = colv[ee1];
                s16x8 v0 = *reinterpret_cast<const s16x8*>(tb + (size_t)r0 * 64);
                s16x8 v1 = *reinterpret_cast<const s16x8*>(tb + (size_t)r1 * 64);
                float m0f = (i0 < deg) ? 1.0f : 0.0f;
                float m1f = (i1 < deg) ? 1.0f : 0.0f;
#pragma unroll
                for (int j = 0; j < 8; ++j)
                    a[j] += m0f * bf2f((unsigned short)v0[j]) + m1f * bf2f((unsigned short)v1[j]);
            }
#pragma unroll
            for (int msk = 8; msk <= 32; msk <<= 1)
#pragma unroll
                for (int j = 0; j < 8; ++j) a[j] += __shfl_xor(a[j], msk);
            if (e8 == 0) {
                float inv = 1.0f / (float)(deg > 0 ? deg : 1);
                s16x8 tr = *reinterpret_cast<const s16x8*>(&sm.tile[local][q * 64 + c8 * 8]);
                s16x8 o;
#pragma unroll
                for (int j = 0; j < 8; ++j) {
                    float v = bf2f((unsigned short)tr[j]) + a[j] * inv;
                    v = v > 0.0f ? v : 0.01f * v;
                    o[j] = (short)f2bf(v);
                }
                *reinterpret_cast<s16x8*>(Fout + (size_t)node * DHID + q * 64 + c8 * 8) = o;
            }
        }
    }
}

// final projection [M,256]bf16 @ [256,2]f32 + b ; one wave per row
__global__ __launch_bounds__(256) void head_k(const unsigned short* __restrict__ f, const float* __restrict__ W,
                                              const float* __restrict__ b, float* __restrict__ outp, int M) {
    int row = blockIdx.x * 4 + (threadIdx.x >> 6);
    if (row >= M) return;
    int lane = threadIdx.x & 63;
    ushort4 v = *reinterpret_cast<const ushort4*>(f + (size_t)row * DHID + lane * 4);
    float4 w0 = *reinterpret_cast<const float4*>(W + lane * 8);
    float4 w1 = *reinterpret_cast<const float4*>(W + lane * 8 + 4);
    float a0 = bf2f(v.x) * w0.x + bf2f(v.y) * w0.z + bf2f(v.z) * w1.x + bf2f(v.w) * w1.z;
    float a1 = bf2f(v.x) * w0.y + bf2f(v.y) * w0.w + bf2f(v.z) * w1.y + bf2f(v.w) * w1.w;
#pragma unroll
    for (int off = 32; off > 0; off >>= 1) {
        a0 += __shfl_down(a0, off);
        a1 += __shfl_down(a1, off);
    }
    if (lane == 0) {
        outp[(size_t)row * 2 + 0] = a0 + b[0];
        outp[(size_t)row * 2 + 1] = a1 + b[1];
    }
}

extern "C" void kernel_launch(void* const* d_in, const int* in_sizes, int n_in,
                              void* d_out, int out_size, void* d_ws, size_t ws_size,
                              hipStream_t stream) {
    const float* x_host  = (const float*)d_in[0];
    const float* x_flow  = (const float*)d_in[1];
    const int*   hf_src  = (const int*)d_in[2];
    const int*   hf_dst  = (const int*)d_in[3];
    const int*   fh_src  = (const int*)d_in[4];
    const int*   fh_dst  = (const int*)d_in[5];
    const float* host_W  = (const float*)d_in[6];
    const float* host_b  = (const float*)d_in[7];
    const float* flow_W  = (const float*)d_in[8];
    const float* flow_b  = (const float*)d_in[9];
    const float* Wl_hf   = (const float*)d_in[10];
    const float* bl_hf   = (const float*)d_in[11];
    const float* Wr_hf   = (const float*)d_in[12];
    const float* Wl_fh   = (const float*)d_in[13];
    const float* bl_fh   = (const float*)d_in[14];
    const float* Wr_fh   = (const float*)d_in[15];
    const float* lin_W   = (const float*)d_in[16];
    const float* lin_b   = (const float*)d_in[17];

    char* ws = (char*)d_ws;
    size_t off = 0;
    auto alloc = [&](size_t bytes) -> char* {
        char* p = ws + off;
        off += (bytes + 255) & ~(size_t)255;
        return p;
    };
    typedef unsigned short u16;
    u16* F     = (u16*)alloc((size_t)NF * DHID * 2);
    u16* H     = (u16*)alloc((size_t)NH * DHID * 2);
    u16* AggH  = (u16*)alloc((size_t)NH * DHID * 2);
    u16* Hpb   = (u16*)alloc((size_t)NH * DHID * 2);   // h' column-blocked [4][NH][64]
    u16* Xf    = (u16*)alloc((size_t)NF * DFLOW * 2);
    u16* Xh    = (u16*)alloc((size_t)NH * DHOST * 2);
    u16* hostWt = (u16*)alloc((size_t)DHID * DHOST * 2);
    u16* flowWt = (u16*)alloc((size_t)DHID * DFLOW * 2);
    u16* WlhfT  = (u16*)alloc((size_t)NLAYER * DHID * DHID * 2);
    u16* WrhfT  = (u16*)alloc((size_t)NLAYER * DHID * DHID * 2);
    u16* WlfhT  = (u16*)alloc((size_t)NLAYER * DHID * DHID * 2);
    u16* WrfhT  = (u16*)alloc((size_t)NLAYER * DHID * DHID * 2);
    float* zbias = (float*)alloc(DHID * 4);
    int* rp_hf  = (int*)alloc((size_t)(NF + 1) * 4);
    int* col_hf = (int*)alloc((size_t)NE * 4);
    int* rp_fh  = (int*)alloc((size_t)(NH + 1) * 4);
    int* col_fh = (int*)alloc((size_t)NE * 4);
    int* pairsA = (int*)alloc((size_t)NE * 4);
    int* pairsB = (int*)alloc((size_t)NE * 4);
    int* gbh2   = (int*)alloc(1024 * 4);
    int* bkoA   = (int*)alloc(513 * 4);
    int* bkoB   = (int*)alloc(513 * 4);
    int* gcurA  = (int*)alloc(512 * 4);
    int* gcurB  = (int*)alloc(512 * 4);
    int* junk   = (int*)alloc(4);
    int* gbhA = gbh2, *gbhB = gbh2 + 512;

    const int NBKT_HF = (NF + 511) / 512;   // 391
    const int NBKT_FH = (NH + 63) / 64;     // 313

    // ---- CSR build, both graphs overlapped ----
    zero_k<<<4, 256, 0, stream>>>(gbh2, 1024);
    histAB<<<dim3((NE + 2047) / 2048, 2), 256, 0, stream>>>(hf_dst, fh_dst, NE, gbhA, gbhB);
    scan1_k<<<1, 256, 0, stream>>>(gbhA, NBKT_HF, bkoA, junk);
    scan1_k<<<1, 256, 0, stream>>>(gbhB, NBKT_FH, bkoB, junk);
    initcur_k<<<2, 256, 0, stream>>>(bkoA, gcurA, NBKT_HF, NE);
    initcur_k<<<2, 256, 0, stream>>>(bkoB, gcurB, NBKT_FH, NE);
    binpassAB<<<dim3((NE + 8191) / 8192, 2), 256, 0, stream>>>(hf_src, hf_dst, fh_src, fh_dst, NE,
                                                               gcurA, gcurB, pairsA, pairsB);
    csrfin<9, 512><<<NBKT_HF, 256, 0, stream>>>(pairsA, bkoA, NF, NE, rp_hf, col_hf);
    csrfin<6, 64><<<NBKT_FH, 256, 0, stream>>>(pairsB, bkoB, NH, NE, rp_fh, col_fh);

    // ---- convert inputs / weights to bf16; zero bias ----
    zero_k<<<1, 256, 0, stream>>>((int*)zbias, DHID);
    cvt_bf16_k<<<(NH * DHOST / 4 + 255) / 256, 256, 0, stream>>>(x_host, Xh, NH * DHOST / 4);
    cvt_bf16_k<<<(NF * DFLOW / 4 + 255) / 256, 256, 0, stream>>>(x_flow, Xf, NF * DFLOW / 4);
    tpose_k<<<dim3(8, DHOST / 32, 1), 256, 0, stream>>>(host_W, hostWt, DHOST);
    tpose_k<<<dim3(8, DFLOW / 32, 1), 256, 0, stream>>>(flow_W, flowWt, DFLOW);
    tpose_k<<<dim3(8, 8, NLAYER), 256, 0, stream>>>(Wl_hf, WlhfT, DHID);
    tpose_k<<<dim3(8, 8, NLAYER), 256, 0, stream>>>(Wr_hf, WrhfT, DHID);
    tpose_k<<<dim3(8, 8, NLAYER), 256, 0, stream>>>(Wl_fh, WlfhT, DHID);
    tpose_k<<<dim3(8, 8, NLAYER), 256, 0, stream>>>(Wr_fh, WrfhT, DHID);

    // ---- input projections (relu) ----
    mgemm<DHOST, 1, 0, 0><<<(NH + 127) / 128, 512, 0, stream>>>(Xh, hostWt, host_b, Xh, hostWt, H, NH);
    mgemm<DFLOW, 1, 0, 0><<<(NF + 127) / 128, 512, 0, stream>>>(Xf, flowWt, flow_b, Xf, flowWt, F, NF);

    // ---- SAGE layers (in-place; both sides consume OLD h,f) ----
    for (int i = 0; i < NLAYER; ++i) {
        const u16* wl_hf = WlhfT + (size_t)i * DHID * DHID;
        const u16* wr_hf = WrhfT + (size_t)i * DHID * DHID;
        const u16* wl_fh = WlfhT + (size_t)i * DHID * DHID;
        const u16* wr_fh = WrfhT + (size_t)i * DHID * DHID;
        const float* b_hf = bl_hf + (size_t)i * DHID;
        const float* b_fh = bl_fh + (size_t)i * DHID;

        // 1) h' = H @ Wl_hf, written column-blocked [4][NH][64]
        mgemm<DHID, 0, 0, 1><<<(NH + 127) / 128, 512, 0, stream>>>(H, wl_hf, zbias, H, wl_hf, Hpb, NH);

        // 2) host-side aggregation from OLD f (deg ~100 -> 8-deep)
        agg8_bf16<<<(NH + 3) / 4, 256, 0, stream>>>(F, rp_fh, col_fh, AggH, NH);

        // 3) fused flow update, in place on F: F = leaky(F@Wr + b + mean_agg(Hp))
        mgemm_fa<<<(NF + 127) / 128, 512, 0, stream>>>(F, wr_hf, b_hf, Hpb, rp_hf, col_hf, F, NF);

        // 4) host update, in-place on H (uses OLD h as root)
        mgemm<DHID, 2, 1, 0><<<(NH + 127) / 128, 512, 0, stream>>>(AggH, wl_fh, b_fh, H, wr_fh, H, NH);
    }

    // ---- output head ----
    head_k<<<(NF + 3) / 4, 256, 0, stream>>>(F, lin_W, lin_b, (float*)d_out, NF);
}

// Round 12
// 989.442 us; speedup vs baseline: 1.4422x; 1.4422x over previous
//
#include <hip/hip_runtime.h>

#define NH    20000
#define NF    200000
#define DHOST 64
#define DFLOW 128
#define DHID  256
#define NE    2000000
#define NLAYER 2

typedef __attribute__((ext_vector_type(8))) short s16x8;
typedef __attribute__((ext_vector_type(4))) float f32x4;

__device__ __forceinline__ unsigned short f2bf(float x) {
    unsigned u = __builtin_bit_cast(unsigned, x);
    unsigned r = (u + 0x7fffu + ((u >> 16) & 1u)) >> 16;
    return (unsigned short)r;
}
__device__ __forceinline__ float bf2f(unsigned short h) {
    unsigned u = ((unsigned)h) << 16;
    return __builtin_bit_cast(float, u);
}

typedef const __attribute__((address_space(1))) unsigned int guint;
typedef __attribute__((address_space(3))) unsigned int luint;
__device__ __forceinline__ void gld16(const void* g, void* l) {
    __builtin_amdgcn_global_load_lds((guint*)g, (luint*)l, 16, 0, 0);
}

// ---------------- small utils ----------------
__global__ void zero_k(int* __restrict__ p, int n) {
    int i = blockIdx.x * 256 + threadIdx.x;
    if (i < n) p[i] = 0;
}

__global__ __launch_bounds__(256) void cvt_bf16_k(const float* __restrict__ in, unsigned short* __restrict__ out, int n4) {
    int i = blockIdx.x * 256 + threadIdx.x;
    if (i < n4) {
        float4 v = *reinterpret_cast<const float4*>(in + (size_t)i * 4);
        ushort4 o;
        o.x = f2bf(v.x); o.y = f2bf(v.y); o.z = f2bf(v.z); o.w = f2bf(v.w);
        *reinterpret_cast<ushort4*>(out + (size_t)i * 4) = o;
    }
}

// W [K][256] f32 -> Wt [256][K] bf16 ; grid (8, K/32, nmat), block 256
__global__ __launch_bounds__(256) void tpose_k(const float* __restrict__ W, unsigned short* __restrict__ Wt, int K) {
    __shared__ float T[32][33];
    int bx = blockIdx.x, by = blockIdx.y;
    const float* Wz = W + (size_t)blockIdx.z * K * 256;
    unsigned short* Wtz = Wt + (size_t)blockIdx.z * K * 256;
    int tx = threadIdx.x & 31, ty = threadIdx.x >> 5;
#pragma unroll
    for (int i = 0; i < 4; ++i) {
        int k = by * 32 + ty + i * 8;
        T[ty + i * 8][tx] = Wz[(size_t)k * 256 + bx * 32 + tx];
    }
    __syncthreads();
#pragma unroll
    for (int i = 0; i < 4; ++i) {
        int n = bx * 32 + ty + i * 8;
        Wtz[(size_t)n * K + by * 32 + tx] = f2bf(T[tx][ty + i * 8]);
    }
}

// exclusive scan, single block (n <= 1024), 256 threads x 4
__global__ void scan1_k(const int* __restrict__ in, int n, int* __restrict__ out, int* __restrict__ bsum) {
    __shared__ int wsum[4];
    int t = threadIdx.x;
    int lane = t & 63, wave = t >> 6;
    int idx = blockIdx.x * 1024 + t * 4;
    int v[4]; int s = 0;
#pragma unroll
    for (int i = 0; i < 4; ++i) { v[i] = (idx + i < n) ? in[idx + i] : 0; s += v[i]; }
    int inc = s;
#pragma unroll
    for (int off = 1; off < 64; off <<= 1) { int u = __shfl_up(inc, off); if (lane >= off) inc += u; }
    if (lane == 63) wsum[wave] = inc;
    __syncthreads();
    int woff = 0;
    for (int w = 0; w < wave; ++w) woff += wsum[w];
    int ex = woff + inc - s;
#pragma unroll
    for (int i = 0; i < 4; ++i) { if (idx + i < n) out[idx + i] = ex; ex += v[i]; }
    if (t == 255) bsum[blockIdx.x] = woff + inc;
}

// ---------------- bucketed CSR build (both graphs per launch) ----------------
__global__ __launch_bounds__(256) void histAB(const int* __restrict__ dstA, const int* __restrict__ dstB,
                                              int E, int* __restrict__ gbhA, int* __restrict__ gbhB) {
    __shared__ int lh[391];
    const int g = blockIdx.y;
    const int* dst = g ? dstB : dstA;
    int* gbh = g ? gbhB : gbhA;
    const int SH = g ? 6 : 9;
    const int NBKT = g ? 313 : 391;
    for (int b = threadIdx.x; b < NBKT; b += 256) lh[b] = 0;
    __syncthreads();
#pragma unroll
    for (int k = 0; k < 8; ++k) {
        int i = blockIdx.x * 2048 + k * 256 + threadIdx.x;
        if (i < E) atomicAdd(&lh[dst[i] >> SH], 1);
    }
    __syncthreads();
    for (int b = threadIdx.x; b < NBKT; b += 256) if (lh[b]) atomicAdd(&gbh[b], lh[b]);
}

__global__ void initcur_k(int* __restrict__ bko, int* __restrict__ gcur, int nbkt, int E) {
    int i = blockIdx.x * 256 + threadIdx.x;
    if (i < nbkt) gcur[i] = bko[i];
    if (i == nbkt) bko[nbkt] = E;
}

__global__ __launch_bounds__(256) void binpassAB(const int* __restrict__ srcA, const int* __restrict__ dstA,
                                                 const int* __restrict__ srcB, const int* __restrict__ dstB,
                                                 int E, int* __restrict__ gcurA, int* __restrict__ gcurB,
                                                 int* __restrict__ pairsA, int* __restrict__ pairsB) {
    __shared__ int lh[391], resv[391], lc[391];
    const int g = blockIdx.y;
    const int* src = g ? srcB : srcA;
    const int* dst = g ? dstB : dstA;
    int* gcur = g ? gcurB : gcurA;
    int* pairs = g ? pairsB : pairsA;
    const int SH = g ? 6 : 9;
    const int NBKT = g ? 313 : 391;
    const int MSK = (1 << SH) - 1;
    const int tid = threadIdx.x;
    const int e0 = blockIdx.x * 8192;
    for (int b = tid; b < NBKT; b += 256) { lh[b] = 0; lc[b] = 0; }
    __syncthreads();
#pragma unroll 4
    for (int k = 0; k < 32; ++k) {
        int i = e0 + k * 256 + tid;
        if (i < E) atomicAdd(&lh[dst[i] >> SH], 1);
    }
    __syncthreads();
    for (int b = tid; b < NBKT; b += 256) if (lh[b]) resv[b] = atomicAdd(&gcur[b], lh[b]);
    __syncthreads();
#pragma unroll 4
    for (int k = 0; k < 32; ++k) {
        int i = e0 + k * 256 + tid;
        if (i < E) {
            int d = dst[i];
            int b = d >> SH;
            int p = resv[b] + atomicAdd(&lc[b], 1);
            pairs[p] = src[i] | ((d & MSK) << 18);
        }
    }
}

template<int SH, int NPB>
__global__ __launch_bounds__(256) void csrfin(const int* __restrict__ pairs, const int* __restrict__ bko,
                                              int N, int E, int* __restrict__ rowptr, int* __restrict__ col) {
    __shared__ int cnt[NPB], pos[NPB];
    __shared__ int wsum[4];
    const int tid = threadIdx.x;
    const int b = blockIdx.x;
    const int nb = b << SH;
    const int beg = bko[b], end = bko[b + 1];
    for (int i = tid; i < NPB; i += 256) cnt[i] = 0;
    __syncthreads();
    for (int i = beg + tid; i < end; i += 256) atomicAdd(&cnt[pairs[i] >> 18], 1);
    __syncthreads();
    int lane = tid & 63, wave = tid >> 6;
    if (NPB == 512) {
        int a = cnt[2 * tid], b2 = cnt[2 * tid + 1];
        int s = a + b2, incl = s;
#pragma unroll
        for (int off = 1; off < 64; off <<= 1) { int u = __shfl_up(incl, off); if (lane >= off) incl += u; }
        if (lane == 63) wsum[wave] = incl;
        __syncthreads();
        int woff = 0;
        for (int w = 0; w < wave; ++w) woff += wsum[w];
        int ex = woff + incl - s;
        pos[2 * tid] = ex; pos[2 * tid + 1] = ex + a;
    } else {
        if (tid < NPB) {
            int a = cnt[tid], incl = a;
#pragma unroll
            for (int off = 1; off < 64; off <<= 1) { int u = __shfl_up(incl, off); if (lane >= off) incl += u; }
            pos[tid] = incl - a;
        }
    }
    __syncthreads();
    for (int i = tid; i < NPB; i += 256) {
        int node = nb + i;
        if (node < N) rowptr[node] = beg + pos[i];
    }
    if (b == gridDim.x - 1 && tid == 0) rowptr[N] = E;
    __syncthreads();
    for (int i = beg + tid; i < end; i += 256) {
        int pk = pairs[i];
        int p = atomicAdd(&pos[pk >> 18], 1);
        col[beg + p] = pk & 0x3FFFF;
    }
}

// ---------------- mean aggregation, 8-deep MLP (high-degree fh graph) ----------------
__global__ __launch_bounds__(256) void agg8_bf16(const unsigned short* __restrict__ srcFeat,
                                                 const int* __restrict__ rowptr,
                                                 const int* __restrict__ col,
                                                 unsigned short* __restrict__ outp, int n) {
    int w = (blockIdx.x << 2) + (threadIdx.x >> 6);
    if (w >= n) return;
    int lane = threadIdx.x & 63;
    int half = lane >> 5, l5 = lane & 31;
    int beg = rowptr[w], end = rowptr[w + 1];
    int T = end - beg;
    const unsigned short* base = srcFeat + l5 * 8;
    float a0[8], a1[8], a2[8], a3[8], a4[8], a5[8], a6[8], a7[8];
#pragma unroll
    for (int j = 0; j < 8; ++j) {
        a0[j] = 0.f; a1[j] = 0.f; a2[j] = 0.f; a3[j] = 0.f;
        a4[j] = 0.f; a5[j] = 0.f; a6[j] = 0.f; a7[j] = 0.f;
    }
    int i = beg;
    int nb16 = T >> 4;
    {
        const int* cp = col + beg + half * 8;
        for (int k = 0; k < nb16; ++k) {
            int c0 = cp[k * 16 + 0], c1 = cp[k * 16 + 1], c2 = cp[k * 16 + 2], c3 = cp[k * 16 + 3];
            int c4 = cp[k * 16 + 4], c5 = cp[k * 16 + 5], c6 = cp[k * 16 + 6], c7 = cp[k * 16 + 7];
            s16x8 v0 = *reinterpret_cast<const s16x8*>(base + (size_t)c0 * DHID);
            s16x8 v1 = *reinterpret_cast<const s16x8*>(base + (size_t)c1 * DHID);
            s16x8 v2 = *reinterpret_cast<const s16x8*>(base + (size_t)c2 * DHID);
            s16x8 v3 = *reinterpret_cast<const s16x8*>(base + (size_t)c3 * DHID);
            s16x8 v4 = *reinterpret_cast<const s16x8*>(base + (size_t)c4 * DHID);
            s16x8 v5 = *reinterpret_cast<const s16x8*>(base + (size_t)c5 * DHID);
            s16x8 v6 = *reinterpret_cast<const s16x8*>(base + (size_t)c6 * DHID);
            s16x8 v7 = *reinterpret_cast<const s16x8*>(base + (size_t)c7 * DHID);
#pragma unroll
            for (int j = 0; j < 8; ++j) {
                a0[j] += bf2f((unsigned short)v0[j]);
                a1[j] += bf2f((unsigned short)v1[j]);
                a2[j] += bf2f((unsigned short)v2[j]);
                a3[j] += bf2f((unsigned short)v3[j]);
                a4[j] += bf2f((unsigned short)v4[j]);
                a5[j] += bf2f((unsigned short)v5[j]);
                a6[j] += bf2f((unsigned short)v6[j]);
                a7[j] += bf2f((unsigned short)v7[j]);
            }
        }
    }
    i += nb16 * 16;
    if (end - i >= 8) {
        const int* cp = col + i + half * 4;
        int c0 = cp[0], c1 = cp[1], c2 = cp[2], c3 = cp[3];
        s16x8 v0 = *reinterpret_cast<const s16x8*>(base + (size_t)c0 * DHID);
        s16x8 v1 = *reinterpret_cast<const s16x8*>(base + (size_t)c1 * DHID);
        s16x8 v2 = *reinterpret_cast<const s16x8*>(base + (size_t)c2 * DHID);
        s16x8 v3 = *reinterpret_cast<const s16x8*>(base + (size_t)c3 * DHID);
#pragma unroll
        for (int j = 0; j < 8; ++j) {
            a0[j] += bf2f((unsigned short)v0[j]);
            a1[j] += bf2f((unsigned short)v1[j]);
            a2[j] += bf2f((unsigned short)v2[j]);
            a3[j] += bf2f((unsigned short)v3[j]);
        }
        i += 8;
    }
    for (int e = i + half; e < end; e += 2) {
        int c = col[e];
        s16x8 v = *reinterpret_cast<const s16x8*>(base + (size_t)c * DHID);
#pragma unroll
        for (int j = 0; j < 8; ++j) a0[j] += bf2f((unsigned short)v[j]);
    }
    int deg = T > 0 ? T : 1;
    float inv = 1.0f / (float)deg;
    s16x8 o;
#pragma unroll
    for (int j = 0; j < 8; ++j) {
        float s = ((a0[j] + a1[j]) + (a2[j] + a3[j])) + ((a4[j] + a5[j]) + (a6[j] + a7[j]));
        s += __shfl_xor(s, 32);
        o[j] = (short)f2bf(s * inv);
    }
    if (half == 0)
        *reinterpret_cast<s16x8*>(outp + (size_t)w * DHID + l5 * 8) = o;
}

// ---------------- MFMA bf16 GEMM, N fixed at 256 ----------------
__device__ __forceinline__ unsigned swz(unsigned r, unsigned cb) {
    return r * 128u + (cb ^ ((r & 7u) << 4));
}

template<int KP>
__device__ __forceinline__ void mfma_pass(const unsigned short* A, const unsigned short* Wt,
                                          int m0, int M, int tid, int lane, int wr, int wc,
                                          f32x4 (&acc)[4][4], char* AsB, char* BsB) {
    const int wave = tid >> 6;
    for (int k0 = 0; k0 < KP; k0 += 64) {
        __syncthreads();
#pragma unroll
        for (int i = 0; i < 2; ++i) {
            int u = wave * 2 + i;
            int r = u * 8 + (lane >> 3);
            int gr = m0 + r; if (gr >= M) gr = M - 1;
            int gs = (lane & 7) ^ (r & 7);
            gld16(A + (size_t)gr * KP + k0 + gs * 8, AsB + u * 1024);
        }
#pragma unroll
        for (int i = 0; i < 4; ++i) {
            int u = wave * 4 + i;
            int nn = u * 8 + (lane >> 3);
            int gs = (lane & 7) ^ (nn & 7);
            gld16(Wt + (size_t)nn * KP + k0 + gs * 8, BsB + u * 1024);
        }
        __syncthreads();
#pragma unroll
        for (int kk = 0; kk < 2; ++kk) {
            s16x8 ar[4], br[4];
            unsigned colb = (unsigned)(kk * 64 + (lane >> 4) * 16);
#pragma unroll
            for (int mf = 0; mf < 4; ++mf)
                ar[mf] = *reinterpret_cast<const s16x8*>(AsB + swz((unsigned)(wr * 64 + mf * 16 + (lane & 15)), colb));
#pragma unroll
            for (int nf = 0; nf < 4; ++nf)
                br[nf] = *reinterpret_cast<const s16x8*>(BsB + swz((unsigned)(wc * 64 + nf * 16 + (lane & 15)), colb));
#pragma unroll
            for (int mf = 0; mf < 4; ++mf)
#pragma unroll
                for (int nf = 0; nf < 4; ++nf)
                    acc[mf][nf] = __builtin_amdgcn_mfma_f32_16x16x32_bf16(ar[mf], br[nf], acc[mf][nf], 0, 0, 0);
        }
    }
}

// BL=0: row-major out [M][256]; BL=1: column-blocked out [4][M][64] (block q = col>>6)
template<int K1, int ACT, int FUSE, int BL>
__global__ __launch_bounds__(512) void mgemm(const unsigned short* A1, const unsigned short* W1t,
                                             const float* __restrict__ bias,
                                             const unsigned short* A2, const unsigned short* W2t,
                                             unsigned short* outp, int M) {
    __shared__ char AsB[128 * 64 * 2];
    __shared__ char BsB[256 * 64 * 2];
    const int tid = threadIdx.x;
    const int lane = tid & 63, wave = tid >> 6;
    const int wr = wave >> 2, wc = wave & 3;
    const int m0 = blockIdx.x * 128;
    f32x4 acc[4][4];
#pragma unroll
    for (int a = 0; a < 4; ++a)
#pragma unroll
        for (int b = 0; b < 4; ++b) acc[a][b] = (f32x4)0.0f;

    mfma_pass<K1>(A1, W1t, m0, M, tid, lane, wr, wc, acc, AsB, BsB);
    if (FUSE) mfma_pass<DHID>(A2, W2t, m0, M, tid, lane, wr, wc, acc, AsB, BsB);

    const int col0 = wc * 64 + (lane & 15);
    float bc[4];
#pragma unroll
    for (int nf = 0; nf < 4; ++nf) bc[nf] = bias[col0 + nf * 16];
#pragma unroll
    for (int mf = 0; mf < 4; ++mf) {
        int row = m0 + wr * 64 + mf * 16 + (lane >> 4) * 4;
#pragma unroll
        for (int j = 0; j < 4; ++j) {
            if (row + j < M) {
#pragma unroll
                for (int nf = 0; nf < 4; ++nf) {
                    float v = acc[mf][nf][j] + bc[nf];
                    if (ACT == 1) v = fmaxf(v, 0.0f);
                    else if (ACT == 2) v = v > 0.0f ? v : 0.01f * v;
                    if (BL)
                        outp[(size_t)wc * M * 64 + (size_t)(row + j) * 64 + (lane & 15) + nf * 16] = f2bf(v);
                    else
                        outp[(size_t)(row + j) * DHID + col0 + nf * 16] = f2bf(v);
                }
            }
        }
    }
}

// ---------------- fused flow update: F = leaky(F@Wr + b + mean_agg(Hp)) ----------------
// GEMM -> bf16 tile in LDS -> 4 column-block gather passes over L2-resident 2.5 MB
// slices. Gather: 8-lane group owns one node; lane owns its 16 B chunk for the whole
// accumulation (no cross-lane reduce, exact-deg trip count, 4-deep unroll).
__global__ __launch_bounds__(512) void mgemm_fa(const unsigned short* Fin, const unsigned short* Wrt,
                                                const float* __restrict__ bias,
                                                const unsigned short* __restrict__ Hpb,  // [4][NH][64]
                                                const int* __restrict__ rowptr,
                                                const int* __restrict__ colv,
                                                unsigned short* Fout, int M) {
    __shared__ union {
        struct { char A[128 * 128]; char B[256 * 128]; } st;   // 48 KB staging
        unsigned short tile[128][256];                         // 64 KB root-term tile
    } sm;
    const int tid = threadIdx.x;
    const int lane = tid & 63, wave = tid >> 6;
    const int wr = wave >> 2, wc = wave & 3;
    const int m0 = blockIdx.x * 128;
    f32x4 acc[4][4];
#pragma unroll
    for (int a = 0; a < 4; ++a)
#pragma unroll
        for (int b = 0; b < 4; ++b) acc[a][b] = (f32x4)0.0f;

    mfma_pass<DHID>(Fin, Wrt, m0, M, tid, lane, wr, wc, acc, sm.st.A, sm.st.B);
    __syncthreads();   // staging reads done before tile overwrites the union

    // epilogue -> LDS tile (bias added, no activation yet)
    const int col0 = wc * 64 + (lane & 15);
    float bc[4];
#pragma unroll
    for (int nf = 0; nf < 4; ++nf) bc[nf] = bias[col0 + nf * 16];
#pragma unroll
    for (int mf = 0; mf < 4; ++mf) {
        int rl = wr * 64 + mf * 16 + (lane >> 4) * 4;
#pragma unroll
        for (int j = 0; j < 4; ++j)
#pragma unroll
            for (int nf = 0; nf < 4; ++nf)
                sm.tile[rl + j][col0 + nf * 16] = f2bf(acc[mf][nf][j] + bc[nf]);
    }
    __syncthreads();

    // gather: 4 column-block passes; 64 groups of 8 lanes; group owns node, 2 rounds
    const int grp = lane >> 3;    // 0..7 within wave
    const int c8  = lane & 7;     // 16 B chunk within 64-col block
    for (int q = 0; q < 4; ++q) {
        const unsigned short* tb = Hpb + (size_t)q * NH * 64 + c8 * 8;
        for (int t = 0; t < 2; ++t) {
            int local = wave * 16 + t * 8 + grp;
            int node = m0 + local;
            int beg = 0, deg = 0;
            if (node < M) { beg = rowptr[node]; deg = rowptr[node + 1] - beg; }
            float a0[8], a1[8];
#pragma unroll
            for (int j = 0; j < 8; ++j) { a0[j] = 0.0f; a1[j] = 0.0f; }
            int i = 0;
            for (; i + 3 < deg; i += 4) {
                int r0 = colv[beg + i + 0];
                int r1 = colv[beg + i + 1];
                int r2 = colv[beg + i + 2];
                int r3 = colv[beg + i + 3];
                s16x8 v0 = *reinterpret_cast<const s16x8*>(tb + (size_t)r0 * 64);
                s16x8 v1 = *reinterpret_cast<const s16x8*>(tb + (size_t)r1 * 64);
                s16x8 v2 = *reinterpret_cast<const s16x8*>(tb + (size_t)r2 * 64);
                s16x8 v3 = *reinterpret_cast<const s16x8*>(tb + (size_t)r3 * 64);
#pragma unroll
                for (int j = 0; j < 8; ++j) {
                    a0[j] += bf2f((unsigned short)v0[j]) + bf2f((unsigned short)v1[j]);
                    a1[j] += bf2f((unsigned short)v2[j]) + bf2f((unsigned short)v3[j]);
                }
            }
            for (; i < deg; ++i) {
                int r = colv[beg + i];
                s16x8 v = *reinterpret_cast<const s16x8*>(tb + (size_t)r * 64);
#pragma unroll
                for (int j = 0; j < 8; ++j) a0[j] += bf2f((unsigned short)v[j]);
            }
            if (node < M) {
                float inv = 1.0f / (float)(deg > 0 ? deg : 1);
                s16x8 tr = *reinterpret_cast<const s16x8*>(&sm.tile[local][q * 64 + c8 * 8]);
                s16x8 o;
#pragma unroll
                for (int j = 0; j < 8; ++j) {
                    float v = bf2f((unsigned short)tr[j]) + (a0[j] + a1[j]) * inv;
                    v = v > 0.0f ? v : 0.01f * v;
                    o[j] = (short)f2bf(v);
                }
                *reinterpret_cast<s16x8*>(Fout + (size_t)node * DHID + q * 64 + c8 * 8) = o;
            }
        }
    }
}

// final projection [M,256]bf16 @ [256,2]f32 + b ; one wave per row
__global__ __launch_bounds__(256) void head_k(const unsigned short* __restrict__ f, const float* __restrict__ W,
                                              const float* __restrict__ b, float* __restrict__ outp, int M) {
    int row = blockIdx.x * 4 + (threadIdx.x >> 6);
    if (row >= M) return;
    int lane = threadIdx.x & 63;
    ushort4 v = *reinterpret_cast<const ushort4*>(f + (size_t)row * DHID + lane * 4);
    float4 w0 = *reinterpret_cast<const float4*>(W + lane * 8);
    float4 w1 = *reinterpret_cast<const float4*>(W + lane * 8 + 4);
    float a0 = bf2f(v.x) * w0.x + bf2f(v.y) * w0.z + bf2f(v.z) * w1.x + bf2f(v.w) * w1.z;
    float a1 = bf2f(v.x) * w0.y + bf2f(v.y) * w0.w + bf2f(v.z) * w1.y + bf2f(v.w) * w1.w;
#pragma unroll
    for (int off = 32; off > 0; off >>= 1) {
        a0 += __shfl_down(a0, off);
        a1 += __shfl_down(a1, off);
    }
    if (lane == 0) {
        outp[(size_t)row * 2 + 0] = a0 + b[0];
        outp[(size_t)row * 2 + 1] = a1 + b[1];
    }
}

extern "C" void kernel_launch(void* const* d_in, const int* in_sizes, int n_in,
                              void* d_out, int out_size, void* d_ws, size_t ws_size,
                              hipStream_t stream) {
    const float* x_host  = (const float*)d_in[0];
    const float* x_flow  = (const float*)d_in[1];
    const int*   hf_src  = (const int*)d_in[2];
    const int*   hf_dst  = (const int*)d_in[3];
    const int*   fh_src  = (const int*)d_in[4];
    const int*   fh_dst  = (const int*)d_in[5];
    const float* host_W  = (const float*)d_in[6];
    const float* host_b  = (const float*)d_in[7];
    const float* flow_W  = (const float*)d_in[8];
    const float* flow_b  = (const float*)d_in[9];
    const float* Wl_hf   = (const float*)d_in[10];
    const float* bl_hf   = (const float*)d_in[11];
    const float* Wr_hf   = (const float*)d_in[12];
    const float* Wl_fh   = (const float*)d_in[13];
    const float* bl_fh   = (const float*)d_in[14];
    const float* Wr_fh   = (const float*)d_in[15];
    const float* lin_W   = (const float*)d_in[16];
    const float* lin_b   = (const float*)d_in[17];

    char* ws = (char*)d_ws;
    size_t off = 0;
    auto alloc = [&](size_t bytes) -> char* {
        char* p = ws + off;
        off += (bytes + 255) & ~(size_t)255;
        return p;
    };
    typedef unsigned short u16;
    u16* F     = (u16*)alloc((size_t)NF * DHID * 2);
    u16* H     = (u16*)alloc((size_t)NH * DHID * 2);
    u16* AggH  = (u16*)alloc((size_t)NH * DHID * 2);
    u16* Hpb   = (u16*)alloc((size_t)NH * DHID * 2);   // h' column-blocked [4][NH][64]
    u16* Xf    = (u16*)alloc((size_t)NF * DFLOW * 2);
    u16* Xh    = (u16*)alloc((size_t)NH * DHOST * 2);
    u16* hostWt = (u16*)alloc((size_t)DHID * DHOST * 2);
    u16* flowWt = (u16*)alloc((size_t)DHID * DFLOW * 2);
    u16* WlhfT  = (u16*)alloc((size_t)NLAYER * DHID * DHID * 2);
    u16* WrhfT  = (u16*)alloc((size_t)NLAYER * DHID * DHID * 2);
    u16* WlfhT  = (u16*)alloc((size_t)NLAYER * DHID * DHID * 2);
    u16* WrfhT  = (u16*)alloc((size_t)NLAYER * DHID * DHID * 2);
    float* zbias = (float*)alloc(DHID * 4);
    int* rp_hf  = (int*)alloc((size_t)(NF + 1) * 4);
    int* col_hf = (int*)alloc((size_t)NE * 4);
    int* rp_fh  = (int*)alloc((size_t)(NH + 1) * 4);
    int* col_fh = (int*)alloc((size_t)NE * 4);
    int* pairsA = (int*)alloc((size_t)NE * 4);
    int* pairsB = (int*)alloc((size_t)NE * 4);
    int* gbh2   = (int*)alloc(1024 * 4);
    int* bkoA   = (int*)alloc(513 * 4);
    int* bkoB   = (int*)alloc(513 * 4);
    int* gcurA  = (int*)alloc(512 * 4);
    int* gcurB  = (int*)alloc(512 * 4);
    int* junk   = (int*)alloc(4);
    int* gbhA = gbh2, *gbhB = gbh2 + 512;

    const int NBKT_HF = (NF + 511) / 512;   // 391
    const int NBKT_FH = (NH + 63) / 64;     // 313

    // ---- CSR build, both graphs overlapped ----
    zero_k<<<4, 256, 0, stream>>>(gbh2, 1024);
    histAB<<<dim3((NE + 2047) / 2048, 2), 256, 0, stream>>>(hf_dst, fh_dst, NE, gbhA, gbhB);
    scan1_k<<<1, 256, 0, stream>>>(gbhA, NBKT_HF, bkoA, junk);
    scan1_k<<<1, 256, 0, stream>>>(gbhB, NBKT_FH, bkoB, junk);
    initcur_k<<<2, 256, 0, stream>>>(bkoA, gcurA, NBKT_HF, NE);
    initcur_k<<<2, 256, 0, stream>>>(bkoB, gcurB, NBKT_FH, NE);
    binpassAB<<<dim3((NE + 8191) / 8192, 2), 256, 0, stream>>>(hf_src, hf_dst, fh_src, fh_dst, NE,
                                                               gcurA, gcurB, pairsA, pairsB);
    csrfin<9, 512><<<NBKT_HF, 256, 0, stream>>>(pairsA, bkoA, NF, NE, rp_hf, col_hf);
    csrfin<6, 64><<<NBKT_FH, 256, 0, stream>>>(pairsB, bkoB, NH, NE, rp_fh, col_fh);

    // ---- convert inputs / weights to bf16; zero bias ----
    zero_k<<<1, 256, 0, stream>>>((int*)zbias, DHID);
    cvt_bf16_k<<<(NH * DHOST / 4 + 255) / 256, 256, 0, stream>>>(x_host, Xh, NH * DHOST / 4);
    cvt_bf16_k<<<(NF * DFLOW / 4 + 255) / 256, 256, 0, stream>>>(x_flow, Xf, NF * DFLOW / 4);
    tpose_k<<<dim3(8, DHOST / 32, 1), 256, 0, stream>>>(host_W, hostWt, DHOST);
    tpose_k<<<dim3(8, DFLOW / 32, 1), 256, 0, stream>>>(flow_W, flowWt, DFLOW);
    tpose_k<<<dim3(8, 8, NLAYER), 256, 0, stream>>>(Wl_hf, WlhfT, DHID);
    tpose_k<<<dim3(8, 8, NLAYER), 256, 0, stream>>>(Wr_hf, WrhfT, DHID);
    tpose_k<<<dim3(8, 8, NLAYER), 256, 0, stream>>>(Wl_fh, WlfhT, DHID);
    tpose_k<<<dim3(8, 8, NLAYER), 256, 0, stream>>>(Wr_fh, WrfhT, DHID);

    // ---- input projections (relu) ----
    mgemm<DHOST, 1, 0, 0><<<(NH + 127) / 128, 512, 0, stream>>>(Xh, hostWt, host_b, Xh, hostWt, H, NH);
    mgemm<DFLOW, 1, 0, 0><<<(NF + 127) / 128, 512, 0, stream>>>(Xf, flowWt, flow_b, Xf, flowWt, F, NF);

    // ---- SAGE layers (in-place; both sides consume OLD h,f) ----
    for (int i = 0; i < NLAYER; ++i) {
        const u16* wl_hf = WlhfT + (size_t)i * DHID * DHID;
        const u16* wr_hf = WrhfT + (size_t)i * DHID * DHID;
        const u16* wl_fh = WlfhT + (size_t)i * DHID * DHID;
        const u16* wr_fh = WrfhT + (size_t)i * DHID * DHID;
        const float* b_hf = bl_hf + (size_t)i * DHID;
        const float* b_fh = bl_fh + (size_t)i * DHID;

        // 1) h' = H @ Wl_hf, written column-blocked [4][NH][64]
        mgemm<DHID, 0, 0, 1><<<(NH + 127) / 128, 512, 0, stream>>>(H, wl_hf, zbias, H, wl_hf, Hpb, NH);

        // 2) host-side aggregation from OLD f (deg ~100 -> 8-deep)
        agg8_bf16<<<(NH + 3) / 4, 256, 0, stream>>>(F, rp_fh, col_fh, AggH, NH);

        // 3) fused flow update, in place on F: F = leaky(F@Wr + b + mean_agg(Hp))
        mgemm_fa<<<(NF + 127) / 128, 512, 0, stream>>>(F, wr_hf, b_hf, Hpb, rp_hf, col_hf, F, NF);

        // 4) host update, in-place on H (uses OLD h as root)
        mgemm<DHID, 2, 1, 0><<<(NH + 127) / 128, 512, 0, stream>>>(AggH, wl_fh, b_fh, H, wr_fh, H, NH);
    }

    // ---- output head ----
    head_k<<<(NF + 3) / 4, 256, 0, stream>>>(F, lin_W, lin_b, (float*)d_out, NF);
}